// Round 1
// baseline (2547.522 us; speedup 1.0000x reference)
//
#include <hip/hip_runtime.h>
#include <math.h>

#define BB 128
#define SS 256
#define HH 512
#define VV 50000
#define VEXT 50012
#define TS 16
#define EPAD 516

__device__ __forceinline__ float fast_tanh(float x) {
  float e = __expf(2.0f * x);
  return 1.0f - 2.0f / (e + 1.0f);
}
__device__ __forceinline__ float fast_sigmoid(float x) {
  return 1.0f / (1.0f + __expf(-x));
}

// K1: prev = prev_state @ Ws_w.T + Ws_b
__global__ void k_prev(const float* __restrict__ prev_state,
                       const float* __restrict__ Ws_w,
                       const float* __restrict__ Ws_b,
                       float* __restrict__ prev) {
  const int b = blockIdx.x, t = threadIdx.x;
  __shared__ float ps[HH];
  ps[t] = prev_state[b * HH + t];
  ps[t + 256] = prev_state[b * HH + t + 256];
  __syncthreads();
  const float4* p4 = (const float4*)ps;
  for (int jj = 0; jj < 2; ++jj) {
    int j = t + jj * 256;
    const float4* w4 = (const float4*)(Ws_w + (size_t)j * HH);
    float acc = 0.f;
    for (int k = 0; k < HH / 4; ++k) {
      float4 w = w4[k], p = p4[k];
      acc += w.x * p.x + w.y * p.y + w.z * p.z + w.w * p.w;
    }
    prev[b * HH + j] = acc + Ws_b[j];
  }
}

// K2: GRU cell -> state (x = [embed[idx], zeros]; only first 512 cols of Wih matter)
__global__ void k_gru(const int* __restrict__ input_idx,
                      const float* __restrict__ embed,
                      const float* __restrict__ prev,
                      const float* __restrict__ Wih,
                      const float* __restrict__ Whh,
                      const float* __restrict__ bih,
                      const float* __restrict__ bhh,
                      float* __restrict__ state,
                      float* __restrict__ state_out) {
  const int b = blockIdx.x, t = threadIdx.x;
  __shared__ float em[HH], pv[HH];
  const int idx = input_idx[b];
  em[t] = embed[(size_t)idx * HH + t];
  em[t + 256] = embed[(size_t)idx * HH + t + 256];
  pv[t] = prev[b * HH + t];
  pv[t + 256] = prev[b * HH + t + 256];
  __syncthreads();
  const float4* e4 = (const float4*)em;
  const float4* p4 = (const float4*)pv;
  for (int hh2 = 0; hh2 < 2; ++hh2) {
    int h = t + hh2 * 256;
    const float4* wr = (const float4*)(Wih + (size_t)h * 1024);
    const float4* wz = (const float4*)(Wih + (size_t)(HH + h) * 1024);
    const float4* wn = (const float4*)(Wih + (size_t)(2 * HH + h) * 1024);
    const float4* ur = (const float4*)(Whh + (size_t)h * HH);
    const float4* uz = (const float4*)(Whh + (size_t)(HH + h) * HH);
    const float4* un = (const float4*)(Whh + (size_t)(2 * HH + h) * HH);
    float ir = 0, iz = 0, inn = 0, hr = 0, hz = 0, hn = 0;
    for (int k = 0; k < HH / 4; ++k) {
      float4 e = e4[k], p = p4[k];
      float4 a;
      a = wr[k]; ir += a.x * e.x + a.y * e.y + a.z * e.z + a.w * e.w;
      a = wz[k]; iz += a.x * e.x + a.y * e.y + a.z * e.z + a.w * e.w;
      a = wn[k]; inn += a.x * e.x + a.y * e.y + a.z * e.z + a.w * e.w;
      a = ur[k]; hr += a.x * p.x + a.y * p.y + a.z * p.z + a.w * p.w;
      a = uz[k]; hz += a.x * p.x + a.y * p.y + a.z * p.z + a.w * p.w;
      a = un[k]; hn += a.x * p.x + a.y * p.y + a.z * p.z + a.w * p.w;
    }
    ir += bih[h]; iz += bih[HH + h]; inn += bih[2 * HH + h];
    hr += bhh[h]; hz += bhh[HH + h]; hn += bhh[2 * HH + h];
    float r = fast_sigmoid(ir + hr);
    float z = fast_sigmoid(iz + hz);
    float n = fast_tanh(inn + r * hn);
    float st = (1.f - z) * n + z * pv[h];
    state[b * HH + h] = st;
    state_out[b * HH + h] = st;
  }
}

// K3: hW[b,j] = state[b,:] . attn_W[j, 0:512] + attn_b[j]
__global__ void k_hw(const float* __restrict__ state,
                     const float* __restrict__ attn_W,
                     const float* __restrict__ attn_b,
                     float* __restrict__ hW) {
  const int b = blockIdx.x, t = threadIdx.x;
  __shared__ float st[HH];
  st[t] = state[b * HH + t];
  st[t + 256] = state[b * HH + t + 256];
  __syncthreads();
  const float4* s4 = (const float4*)st;
  for (int jj = 0; jj < 2; ++jj) {
    int j = t + jj * 256;
    const float4* w4 = (const float4*)(attn_W + (size_t)j * 1024);
    float acc = 0.f;
    for (int k = 0; k < HH / 4; ++k) {
      float4 w = w4[k], p = s4[k];
      acc += w.x * p.x + w.y * p.y + w.z * p.z + w.w * p.w;
    }
    hW[b * HH + j] = acc + attn_b[j];
  }
}

// K4: attn score[b,s] = sum_j tanh(hW[b,j] + enc[b,s,:].attn_W[j,512:]) * v[j]
__global__ __launch_bounds__(128) void k_attn_score(
    const float* __restrict__ enc,
    const float* __restrict__ attn_W,
    const float* __restrict__ hW,
    const float* __restrict__ attn_v,
    float* __restrict__ score) {
  const int b = blockIdx.x, stile = blockIdx.y, t = threadIdx.x;
  __shared__ float el[TS * EPAD];
  __shared__ float red[TS * 129];
  const float* ebase = enc + ((size_t)(b * SS + stile * TS)) * HH;
  for (int s = 0; s < TS; ++s) {
    float4 v = ((const float4*)(ebase + s * HH))[t];
    *((float4*)(el + s * EPAD + 4 * t)) = v;
  }
  __syncthreads();
  float acc[4][TS];
#pragma unroll
  for (int jj = 0; jj < 4; ++jj)
#pragma unroll
    for (int s = 0; s < TS; ++s) acc[jj][s] = 0.f;
  for (int k4 = 0; k4 < HH; k4 += 4) {
    float4 w[4];
#pragma unroll
    for (int jj = 0; jj < 4; ++jj)
      w[jj] = *(const float4*)(attn_W + (size_t)(t + jj * 128) * 1024 + HH + k4);
#pragma unroll
    for (int s = 0; s < TS; ++s) {
      float4 e = *(const float4*)(el + s * EPAD + k4);
#pragma unroll
      for (int jj = 0; jj < 4; ++jj)
        acc[jj][s] += w[jj].x * e.x + w[jj].y * e.y + w[jj].z * e.z + w[jj].w * e.w;
    }
  }
  float part[TS];
#pragma unroll
  for (int s = 0; s < TS; ++s) part[s] = 0.f;
#pragma unroll
  for (int jj = 0; jj < 4; ++jj) {
    int j = t + jj * 128;
    float hwv = hW[b * HH + j];
    float vv = attn_v[j];
#pragma unroll
    for (int s = 0; s < TS; ++s)
      part[s] += fast_tanh(acc[jj][s] + hwv) * vv;
  }
  for (int s = 0; s < TS; ++s) red[s * 129 + t] = part[s];
  __syncthreads();
  if (t < TS) {
    float tot = 0.f;
    for (int i = 0; i < 128; ++i) tot += red[t * 129 + i];
    score[b * SS + stile * TS + t] = tot;
  }
}

// K5: softmax over s + context; assemble y = [state, context]
__global__ void k_softmax_ctx(const float* __restrict__ score,
                              const float* __restrict__ enc,
                              const float* __restrict__ state,
                              float* __restrict__ y) {
  const int b = blockIdx.x, t = threadIdx.x;
  __shared__ float sw[SS];
  __shared__ float rbuf[24];
  float x = score[b * SS + t];
  float m = x;
  for (int off = 32; off > 0; off >>= 1) m = fmaxf(m, __shfl_down(m, off, 64));
  if ((t & 63) == 0) rbuf[t >> 6] = m;
  __syncthreads();
  if (t == 0) rbuf[8] = fmaxf(fmaxf(rbuf[0], rbuf[1]), fmaxf(rbuf[2], rbuf[3]));
  __syncthreads();
  float M = rbuf[8];
  float e = __expf(x - M);
  float ssum = e;
  for (int off = 32; off > 0; off >>= 1) ssum += __shfl_down(ssum, off, 64);
  if ((t & 63) == 0) rbuf[16 + (t >> 6)] = ssum;
  __syncthreads();
  if (t == 0) rbuf[9] = rbuf[16] + rbuf[17] + rbuf[18] + rbuf[19];
  __syncthreads();
  sw[t] = e / rbuf[9];
  __syncthreads();
  for (int hh2 = 0; hh2 < 2; ++hh2) {
    int h = t + hh2 * 256;
    float acc = 0.f;
    for (int s = 0; s < SS; ++s)
      acc += sw[s] * enc[((size_t)(b * SS + s)) * HH + h];
    y[b * 1024 + HH + h] = acc;
    y[b * 1024 + h] = state[b * HH + h];
  }
}

// K6: score_g = y @ Wo_w.T + Wo_b   (128 x 50000, K=1024)
__global__ __launch_bounds__(256) void k_score_g(
    const float* __restrict__ y,
    const float* __restrict__ Wo_w,
    const float* __restrict__ Wo_b,
    float* __restrict__ sg) {
  const int t = threadIdx.x;
  const int vbase = blockIdx.x * 64;
  __shared__ float ylds[32 * 128];
  __shared__ float wlds[32 * 64];
  const int tx = t & 15;
  const int ty = t >> 4;
  float acc[8][4];
#pragma unroll
  for (int i = 0; i < 8; ++i)
#pragma unroll
    for (int j = 0; j < 4; ++j) acc[i][j] = 0.f;
  const int lb = t & 127, lhalf = t >> 7;
  const int lv = t & 63, lq = t >> 6;
  const int v_ld = min(vbase + lv, VV - 1);
  for (int kt = 0; kt < 1024; kt += 32) {
    {
      const float* yb = y + (size_t)lb * 1024 + kt + lhalf * 16;
#pragma unroll
      for (int i = 0; i < 4; ++i) {
        float4 vv = ((const float4*)yb)[i];
        int k = lhalf * 16 + i * 4;
        ylds[(k + 0) * 128 + lb] = vv.x;
        ylds[(k + 1) * 128 + lb] = vv.y;
        ylds[(k + 2) * 128 + lb] = vv.z;
        ylds[(k + 3) * 128 + lb] = vv.w;
      }
    }
    {
      const float* wb = Wo_w + (size_t)v_ld * 1024 + kt + lq * 8;
#pragma unroll
      for (int i = 0; i < 2; ++i) {
        float4 vv = ((const float4*)wb)[i];
        int k = lq * 8 + i * 4;
        wlds[(k + 0) * 64 + lv] = vv.x;
        wlds[(k + 1) * 64 + lv] = vv.y;
        wlds[(k + 2) * 64 + lv] = vv.z;
        wlds[(k + 3) * 64 + lv] = vv.w;
      }
    }
    __syncthreads();
#pragma unroll 4
    for (int kk = 0; kk < 32; ++kk) {
      float4 a0 = *(const float4*)(ylds + kk * 128 + ty * 8);
      float4 a1 = *(const float4*)(ylds + kk * 128 + ty * 8 + 4);
      float4 w = *(const float4*)(wlds + kk * 64 + tx * 4);
      float av[8] = {a0.x, a0.y, a0.z, a0.w, a1.x, a1.y, a1.z, a1.w};
      float wv[4] = {w.x, w.y, w.z, w.w};
#pragma unroll
      for (int i = 0; i < 8; ++i)
#pragma unroll
        for (int j = 0; j < 4; ++j) acc[i][j] += av[i] * wv[j];
    }
    __syncthreads();
  }
#pragma unroll
  for (int j = 0; j < 4; ++j) {
    int v = vbase + tx * 4 + j;
    if (v < VV) {
      float bias = Wo_b[v];
#pragma unroll
      for (int i = 0; i < 8; ++i) {
        int bb = ty * 8 + i;
        sg[(size_t)bb * VV + v] = acc[i][j] + bias;
      }
    }
  }
}

// K7: score_c[b,s] = sum_n tanh(enc[b,s,:].Wc_w[n,:] + Wc_b[n]) * y[b,n]  (+ mask)
__global__ __launch_bounds__(128) void k_score_c(
    const float* __restrict__ enc,
    const float* __restrict__ Wc_w,
    const float* __restrict__ Wc_b,
    const float* __restrict__ y,
    const int* __restrict__ enc_idx,
    float* __restrict__ sc_out) {
  const int b = blockIdx.x, stile = blockIdx.y, t = threadIdx.x;
  __shared__ float el[TS * EPAD];
  __shared__ float red[TS * 129];
  const float* ebase = enc + ((size_t)(b * SS + stile * TS)) * HH;
  for (int s = 0; s < TS; ++s) {
    float4 v = ((const float4*)(ebase + s * HH))[t];
    *((float4*)(el + s * EPAD + 4 * t)) = v;
  }
  __syncthreads();
  float part[TS];
#pragma unroll
  for (int s = 0; s < TS; ++s) part[s] = 0.f;
  for (int pass = 0; pass < 2; ++pass) {
    const int nbase = pass * 512;
    float acc[4][TS];
#pragma unroll
    for (int jj = 0; jj < 4; ++jj)
#pragma unroll
      for (int s = 0; s < TS; ++s) acc[jj][s] = 0.f;
    for (int k4 = 0; k4 < HH; k4 += 4) {
      float4 w[4];
#pragma unroll
      for (int jj = 0; jj < 4; ++jj)
        w[jj] = *(const float4*)(Wc_w + (size_t)(nbase + t + jj * 128) * HH + k4);
#pragma unroll
      for (int s = 0; s < TS; ++s) {
        float4 e = *(const float4*)(el + s * EPAD + k4);
#pragma unroll
        for (int jj = 0; jj < 4; ++jj)
          acc[jj][s] += w[jj].x * e.x + w[jj].y * e.y + w[jj].z * e.z + w[jj].w * e.w;
      }
    }
#pragma unroll
    for (int jj = 0; jj < 4; ++jj) {
      int n = nbase + t + jj * 128;
      float bb2 = Wc_b[n];
      float yv = y[b * 1024 + n];
#pragma unroll
      for (int s = 0; s < TS; ++s)
        part[s] += fast_tanh(acc[jj][s] + bb2) * yv;
    }
  }
  for (int s = 0; s < TS; ++s) red[s * 129 + t] = part[s];
  __syncthreads();
  if (t < TS) {
    float tot = 0.f;
    for (int i = 0; i < 128; ++i) tot += red[t * 129 + i];
    int sidx = stile * TS + t;
    if (enc_idx[b * SS + sidx] == 0) tot -= 1000.0f;
    sc_out[b * SS + sidx] = tot;
  }
}

// K8a: per-row max & sum over [score_g | score_c]
__global__ void k_rowstat(const float* __restrict__ sg,
                          const float* __restrict__ sc,
                          float* __restrict__ rmax,
                          float* __restrict__ rsum) {
  const int b = blockIdx.x, t = threadIdx.x;
  __shared__ float rbuf[8];
  const float* row = sg + (size_t)b * VV;
  float m = -1e30f;
  for (int i = t; i < VV; i += 256) m = fmaxf(m, row[i]);
  m = fmaxf(m, sc[b * SS + t]);
  for (int off = 32; off > 0; off >>= 1) m = fmaxf(m, __shfl_down(m, off, 64));
  if ((t & 63) == 0) rbuf[t >> 6] = m;
  __syncthreads();
  if (t == 0) rbuf[4] = fmaxf(fmaxf(rbuf[0], rbuf[1]), fmaxf(rbuf[2], rbuf[3]));
  __syncthreads();
  float M = rbuf[4];
  float ssum = __expf(sc[b * SS + t] - M);
  for (int i = t; i < VV; i += 256) ssum += __expf(row[i] - M);
  for (int off = 32; off > 0; off >>= 1) ssum += __shfl_down(ssum, off, 64);
  if ((t & 63) == 0) rbuf[t >> 6] = ssum;
  __syncthreads();
  if (t == 0) {
    rmax[b] = M;
    rsum[b] = rbuf[0] + rbuf[1] + rbuf[2] + rbuf[3];
  }
}

// K8b: out[b, :] = prob_g (v < V) else 1e-4 (OOV slots)
__global__ void k_write_probg(const float* __restrict__ sg,
                              const float* __restrict__ rmax,
                              const float* __restrict__ rsum,
                              float* __restrict__ out) {
  int i = blockIdx.x * 256 + threadIdx.x;
  const int total = BB * VEXT;
  if (i >= total) return;
  int b = i / VEXT;
  int v = i - b * VEXT;
  float val;
  if (v < VV)
    val = __expf(sg[(size_t)b * VV + v] - rmax[b]) / rsum[b];
  else
    val = 1e-4f;
  out[i] = val;
}

// K8c: prob_c, scatter-add into out, global pc_total
__global__ void k_probc(const float* __restrict__ sc,
                        const int* __restrict__ enc_idx,
                        const float* __restrict__ rmax,
                        const float* __restrict__ rsum,
                        float* __restrict__ prob_c,
                        float* __restrict__ out,
                        float* __restrict__ pc_total) {
  const int b = blockIdx.x, t = threadIdx.x;
  __shared__ float rbuf[8];
  float pc = __expf(sc[b * SS + t] - rmax[b]) / rsum[b];
  prob_c[b * SS + t] = pc;
  atomicAdd(&out[(size_t)b * VEXT + enc_idx[b * SS + t]], pc);
  float ssum = pc;
  for (int off = 32; off > 0; off >>= 1) ssum += __shfl_down(ssum, off, 64);
  if ((t & 63) == 0) rbuf[t >> 6] = ssum;
  __syncthreads();
  if (t == 0) atomicAdd(pc_total, rbuf[0] + rbuf[1] + rbuf[2] + rbuf[3]);
}

// K9: weighted_new
__global__ void k_weighted(const int* __restrict__ enc_idx,
                           const int* __restrict__ input_idx,
                           const float* __restrict__ prob_c,
                           const float* __restrict__ pc_total,
                           const float* __restrict__ enc,
                           float* __restrict__ wout) {
  const int b = blockIdx.x, t = threadIdx.x;
  __shared__ float f[SS];
  __shared__ float rbuf[8];
  int match = (enc_idx[b * SS + t] == input_idx[b]) ? 1 : 0;
  float ssum = (float)match;
  for (int off = 32; off > 0; off >>= 1) ssum += __shfl_down(ssum, off, 64);
  if ((t & 63) == 0) rbuf[t >> 6] = ssum;
  __syncthreads();
  if (t == 0) rbuf[4] = rbuf[0] + rbuf[1] + rbuf[2] + rbuf[3];
  __syncthreads();
  float tot = rbuf[4];
  if (tot == 0.0f) {
    wout[b * HH + t] = 0.f;
    wout[b * HH + t + 256] = 0.f;
    return;
  }
  float norm = (tot > 1.0f) ? 1.0f / tot : 1.0f;
  float inv_pct = 1.0f / pc_total[0];
  f[t] = match ? prob_c[b * SS + t] * inv_pct * norm : 0.f;
  __syncthreads();
  for (int hh2 = 0; hh2 < 2; ++hh2) {
    int h = t + hh2 * 256;
    float acc = 0.f;
    for (int s = 0; s < SS; ++s)
      acc += f[s] * enc[((size_t)(b * SS + s)) * HH + h];
    wout[b * HH + h] = acc;
  }
}

extern "C" void kernel_launch(void* const* d_in, const int* in_sizes, int n_in,
                              void* d_out, int out_size, void* d_ws, size_t ws_size,
                              hipStream_t stream) {
  const int* input_idx = (const int*)d_in[0];
  const float* encoded = (const float*)d_in[1];
  const int* encoded_idx = (const int*)d_in[2];
  const float* prev_state = (const float*)d_in[3];
  const float* embed = (const float*)d_in[5];
  const float* Ws_w = (const float*)d_in[6];
  const float* Ws_b = (const float*)d_in[7];
  const float* gWih = (const float*)d_in[8];
  const float* gWhh = (const float*)d_in[9];
  const float* gbih = (const float*)d_in[10];
  const float* gbhh = (const float*)d_in[11];
  const float* attn_W = (const float*)d_in[12];
  const float* attn_b = (const float*)d_in[13];
  const float* attn_v = (const float*)d_in[14];
  const float* Wo_w = (const float*)d_in[15];
  const float* Wo_b = (const float*)d_in[16];
  const float* Wc_w = (const float*)d_in[17];
  const float* Wc_b = (const float*)d_in[18];

  float* out = (float*)d_out;
  float* out_state = out + (size_t)BB * VEXT;
  float* out_weighted = out_state + BB * HH;

  float* ws = (float*)d_ws;
  float* prev = ws;
  float* state = prev + BB * HH;
  float* hW = state + BB * HH;
  float* ascore = hW + BB * HH;
  float* y = ascore + BB * SS;
  float* sg = y + BB * 1024;
  float* sc = sg + (size_t)BB * VV;
  float* prob_c = sc + BB * SS;
  float* rmax = prob_c + BB * SS;
  float* rsum = rmax + BB;
  float* pc_total = rsum + BB;

  hipMemsetAsync(pc_total, 0, sizeof(float), stream);

  k_prev<<<BB, 256, 0, stream>>>(prev_state, Ws_w, Ws_b, prev);
  k_gru<<<BB, 256, 0, stream>>>(input_idx, embed, prev, gWih, gWhh, gbih, gbhh,
                                state, out_state);
  k_hw<<<BB, 256, 0, stream>>>(state, attn_W, attn_b, hW);
  k_attn_score<<<dim3(BB, SS / TS), 128, 0, stream>>>(encoded, attn_W, hW, attn_v, ascore);
  k_softmax_ctx<<<BB, 256, 0, stream>>>(ascore, encoded, state, y);
  k_score_g<<<(VV + 63) / 64, 256, 0, stream>>>(y, Wo_w, Wo_b, sg);
  k_score_c<<<dim3(BB, SS / TS), 128, 0, stream>>>(encoded, Wc_w, Wc_b, y, encoded_idx, sc);
  k_rowstat<<<BB, 256, 0, stream>>>(sg, sc, rmax, rsum);
  k_write_probg<<<(BB * VEXT + 255) / 256, 256, 0, stream>>>(sg, rmax, rsum, out);
  k_probc<<<BB, 256, 0, stream>>>(sc, encoded_idx, rmax, rsum, prob_c, out, pc_total);
  k_weighted<<<BB, 256, 0, stream>>>(encoded_idx, input_idx, prob_c, pc_total,
                                     encoded, out_weighted);
}

// Round 2
// 1166.797 us; speedup vs baseline: 2.1833x; 2.1833x over previous
//
#include <hip/hip_runtime.h>
#include <hip/hip_bf16.h>
#include <math.h>

#define BB 128
#define SS 256
#define HH 512
#define VV 50000
#define VEXT 50012

typedef __bf16 bf16x8 __attribute__((ext_vector_type(8)));
typedef float f32x4 __attribute__((ext_vector_type(4)));

__device__ __forceinline__ float fast_tanh(float x) {
  float e = __expf(2.0f * x);
  return 1.0f - 2.0f / (e + 1.0f);
}
__device__ __forceinline__ float fast_sigmoid(float x) {
  return 1.0f / (1.0f + __expf(-x));
}
__device__ __forceinline__ bf16x8 cvt8(const float* p) {
  float4 a = *(const float4*)p;
  float4 b = *(const float4*)(p + 4);
  bf16x8 r;
  r[0] = (__bf16)a.x; r[1] = (__bf16)a.y; r[2] = (__bf16)a.z; r[3] = (__bf16)a.w;
  r[4] = (__bf16)b.x; r[5] = (__bf16)b.y; r[6] = (__bf16)b.z; r[7] = (__bf16)b.w;
  return r;
}

// ---- weight bf16 pre-conversion ----
__global__ void k_cvt_wc(const float* __restrict__ w, __hip_bfloat16* __restrict__ o) {
  int i = blockIdx.x * 256 + threadIdx.x;  // 131072 float4s
  if (i >= 131072) return;
  float4 v = ((const float4*)w)[i];
  __hip_bfloat16* d = o + i * 4;
  d[0] = __float2bfloat16(v.x); d[1] = __float2bfloat16(v.y);
  d[2] = __float2bfloat16(v.z); d[3] = __float2bfloat16(v.w);
}
__global__ void k_cvt_wa2(const float* __restrict__ attn_W, __hip_bfloat16* __restrict__ o) {
  int i = blockIdx.x * 256 + threadIdx.x;  // 65536 float4s over [512][512] extract
  if (i >= 65536) return;
  int j = i >> 7, c4 = i & 127;
  float4 v = *(const float4*)(attn_W + (size_t)j * 1024 + HH + c4 * 4);
  __hip_bfloat16* d = o + (size_t)j * HH + c4 * 4;
  d[0] = __float2bfloat16(v.x); d[1] = __float2bfloat16(v.y);
  d[2] = __float2bfloat16(v.z); d[3] = __float2bfloat16(v.w);
}

// ---- small GEMV-ish kernels (unchanged) ----
__global__ void k_prev(const float* __restrict__ prev_state,
                       const float* __restrict__ Ws_w,
                       const float* __restrict__ Ws_b,
                       float* __restrict__ prev) {
  const int b = blockIdx.x, t = threadIdx.x;
  __shared__ float ps[HH];
  ps[t] = prev_state[b * HH + t];
  ps[t + 256] = prev_state[b * HH + t + 256];
  __syncthreads();
  const float4* p4 = (const float4*)ps;
  for (int jj = 0; jj < 2; ++jj) {
    int j = t + jj * 256;
    const float4* w4 = (const float4*)(Ws_w + (size_t)j * HH);
    float acc = 0.f;
    for (int k = 0; k < HH / 4; ++k) {
      float4 w = w4[k], p = p4[k];
      acc += w.x * p.x + w.y * p.y + w.z * p.z + w.w * p.w;
    }
    prev[b * HH + j] = acc + Ws_b[j];
  }
}

__global__ void k_gru(const int* __restrict__ input_idx,
                      const float* __restrict__ embed,
                      const float* __restrict__ prev,
                      const float* __restrict__ Wih,
                      const float* __restrict__ Whh,
                      const float* __restrict__ bih,
                      const float* __restrict__ bhh,
                      float* __restrict__ state,
                      float* __restrict__ state_out) {
  const int b = blockIdx.x, t = threadIdx.x;
  __shared__ float em[HH], pv[HH];
  const int idx = input_idx[b];
  em[t] = embed[(size_t)idx * HH + t];
  em[t + 256] = embed[(size_t)idx * HH + t + 256];
  pv[t] = prev[b * HH + t];
  pv[t + 256] = prev[b * HH + t + 256];
  __syncthreads();
  const float4* e4 = (const float4*)em;
  const float4* p4 = (const float4*)pv;
  for (int hh2 = 0; hh2 < 2; ++hh2) {
    int h = t + hh2 * 256;
    const float4* wr = (const float4*)(Wih + (size_t)h * 1024);
    const float4* wz = (const float4*)(Wih + (size_t)(HH + h) * 1024);
    const float4* wn = (const float4*)(Wih + (size_t)(2 * HH + h) * 1024);
    const float4* ur = (const float4*)(Whh + (size_t)h * HH);
    const float4* uz = (const float4*)(Whh + (size_t)(HH + h) * HH);
    const float4* un = (const float4*)(Whh + (size_t)(2 * HH + h) * HH);
    float ir = 0, iz = 0, inn = 0, hr = 0, hz = 0, hn = 0;
    for (int k = 0; k < HH / 4; ++k) {
      float4 e = e4[k], p = p4[k];
      float4 a;
      a = wr[k]; ir += a.x * e.x + a.y * e.y + a.z * e.z + a.w * e.w;
      a = wz[k]; iz += a.x * e.x + a.y * e.y + a.z * e.z + a.w * e.w;
      a = wn[k]; inn += a.x * e.x + a.y * e.y + a.z * e.z + a.w * e.w;
      a = ur[k]; hr += a.x * p.x + a.y * p.y + a.z * p.z + a.w * p.w;
      a = uz[k]; hz += a.x * p.x + a.y * p.y + a.z * p.z + a.w * p.w;
      a = un[k]; hn += a.x * p.x + a.y * p.y + a.z * p.z + a.w * p.w;
    }
    ir += bih[h]; iz += bih[HH + h]; inn += bih[2 * HH + h];
    hr += bhh[h]; hz += bhh[HH + h]; hn += bhh[2 * HH + h];
    float r = fast_sigmoid(ir + hr);
    float z = fast_sigmoid(iz + hz);
    float n = fast_tanh(inn + r * hn);
    float st = (1.f - z) * n + z * pv[h];
    state[b * HH + h] = st;
    state_out[b * HH + h] = st;
  }
}

__global__ void k_hw(const float* __restrict__ state,
                     const float* __restrict__ attn_W,
                     const float* __restrict__ attn_b,
                     float* __restrict__ hW) {
  const int b = blockIdx.x, t = threadIdx.x;
  __shared__ float st[HH];
  st[t] = state[b * HH + t];
  st[t + 256] = state[b * HH + t + 256];
  __syncthreads();
  const float4* s4 = (const float4*)st;
  for (int jj = 0; jj < 2; ++jj) {
    int j = t + jj * 256;
    const float4* w4 = (const float4*)(attn_W + (size_t)j * 1024);
    float acc = 0.f;
    for (int k = 0; k < HH / 4; ++k) {
      float4 w = w4[k], p = s4[k];
      acc += w.x * p.x + w.y * p.y + w.z * p.z + w.w * p.w;
    }
    hW[b * HH + j] = acc + attn_b[j];
  }
}

// ---- fused MFMA kernel: out[b,s] = sum_n tanh(enc[b,s,:].W[n,:] + bias[n]) * mult[n]
// MODE 0: attn (bias = hW[b,:], mult = attn_v), MODE 1: score_c (bias = Wc_b, mult = y[b,:], +mask)
template <int NTOT, int MODE>
__global__ __launch_bounds__(256, 2) void k_fused(
    const float* __restrict__ enc, const __hip_bfloat16* __restrict__ Wbf,
    const float* __restrict__ biasA, const float* __restrict__ multA,
    const int* __restrict__ enc_idx, float* __restrict__ out) {
  const int b = blockIdx.x, s0 = blockIdx.y * 32, t = threadIdx.x;
  const int l = t & 63, w = t >> 6;
  const int wm = w & 1, wn = w >> 1;
  const int m = l & 15, q = l >> 4;
  const int row = s0 + wm * 16 + m;
  const float* erow = enc + ((size_t)b * SS + row) * HH;
  // A fragments for entire K=512 held in registers (16 frags x 4 VGPR)
  bf16x8 afr[16];
#pragma unroll
  for (int ks = 0; ks < 16; ++ks) afr[ks] = cvt8(erow + ks * 32 + q * 8);

  const float* bias_base = (MODE == 0) ? biasA + (size_t)b * HH : biasA;
  const float* mult_base = (MODE == 0) ? multA : multA + (size_t)b * 1024;

  float part[4] = {0.f, 0.f, 0.f, 0.f};
  for (int nb = 0; nb < NTOT; nb += 32) {
    const int n = nb + wn * 16 + m;
    const __hip_bfloat16* wrow = Wbf + (size_t)n * HH;
    f32x4 acc = {0.f, 0.f, 0.f, 0.f};
#pragma unroll
    for (int ks = 0; ks < 16; ++ks) {
      bf16x8 bfr = *(const bf16x8*)(wrow + ks * 32 + q * 8);
      acc = __builtin_amdgcn_mfma_f32_16x16x32_bf16(afr[ks], bfr, acc, 0, 0, 0);
    }
    float bias = bias_base[n];
    float mul = mult_base[n];
#pragma unroll
    for (int r = 0; r < 4; ++r) part[r] += fast_tanh(acc[r] + bias) * mul;
  }
  // reduce over the 16 col-lanes (same q group)
#pragma unroll
  for (int r = 0; r < 4; ++r) {
    part[r] += __shfl_xor(part[r], 1, 64);
    part[r] += __shfl_xor(part[r], 2, 64);
    part[r] += __shfl_xor(part[r], 4, 64);
    part[r] += __shfl_xor(part[r], 8, 64);
  }
  __shared__ float red[2][32];
  if (m == 0) {
#pragma unroll
    for (int r = 0; r < 4; ++r) red[wn][wm * 16 + q * 4 + r] = part[r];
  }
  __syncthreads();
  if (t < 32) {
    float v = red[0][t] + red[1][t];
    int s = s0 + t;
    if (MODE == 1 && enc_idx[b * SS + s] == 0) v -= 1000.0f;
    out[b * SS + s] = v;
  }
}

// ---- score_g via MFMA: sg(128 x 50000) = y(128x1024) @ Wo_w^T, fp32->bf16 in-reg ----
__global__ __launch_bounds__(256, 2) void k_score_g_mfma(
    const float* __restrict__ y, const float* __restrict__ Wo_w,
    const float* __restrict__ Wo_b, float* __restrict__ sg) {
  __shared__ __hip_bfloat16 ylds[128 * 72];  // 64 K-cols + 8 pad per row
  const int t = threadIdx.x;
  const int l = t & 63, w = t >> 6;  // w = wn (4 waves x 16 n)
  const int m = l & 15, q = l >> 4;
  const int nb = blockIdx.x * 64;
  const int n = nb + w * 16 + m;
  const int n_ld = (n < VV) ? n : (VV - 1);
  const float* wrow = Wo_w + (size_t)n_ld * 1024;
  f32x4 acc[8];
#pragma unroll
  for (int mt = 0; mt < 8; ++mt) acc[mt] = (f32x4){0.f, 0.f, 0.f, 0.f};

  for (int kt = 0; kt < 1024; kt += 64) {
    __syncthreads();
#pragma unroll
    for (int i = 0; i < 8; ++i) {
      int f = t + i * 256;
      int row = f >> 4, c4 = f & 15;
      float4 v = *(const float4*)(y + (size_t)row * 1024 + kt + c4 * 4);
      __hip_bfloat16* d = ylds + row * 72 + c4 * 4;
      d[0] = __float2bfloat16(v.x); d[1] = __float2bfloat16(v.y);
      d[2] = __float2bfloat16(v.z); d[3] = __float2bfloat16(v.w);
    }
    __syncthreads();
#pragma unroll
    for (int ksl = 0; ksl < 2; ++ksl) {
      bf16x8 bfr = cvt8(wrow + kt + ksl * 32 + q * 8);
#pragma unroll
      for (int mt = 0; mt < 8; ++mt) {
        bf16x8 af = *(const bf16x8*)(ylds + (mt * 16 + m) * 72 + ksl * 32 + q * 8);
        acc[mt] = __builtin_amdgcn_mfma_f32_16x16x32_bf16(af, bfr, acc[mt], 0, 0, 0);
      }
    }
  }
  if (n < VV) {
    float bias = Wo_b[n];
#pragma unroll
    for (int mt = 0; mt < 8; ++mt) {
#pragma unroll
      for (int r = 0; r < 4; ++r) {
        int rowm = mt * 16 + q * 4 + r;
        sg[(size_t)rowm * VV + n] = acc[mt][r] + bias;
      }
    }
  }
}

// ---- attention softmax -> aw ----
__global__ void k_attn_softmax(const float* __restrict__ score, float* __restrict__ aw) {
  const int b = blockIdx.x, t = threadIdx.x;
  __shared__ float rbuf[8];
  __shared__ float MS[2];
  float x = score[b * SS + t];
  float m = x;
  for (int off = 32; off > 0; off >>= 1) m = fmaxf(m, __shfl_xor(m, off, 64));
  if ((t & 63) == 0) rbuf[t >> 6] = m;
  __syncthreads();
  if (t == 0) MS[0] = fmaxf(fmaxf(rbuf[0], rbuf[1]), fmaxf(rbuf[2], rbuf[3]));
  __syncthreads();
  float e = __expf(x - MS[0]);
  float s = e;
  for (int off = 32; off > 0; off >>= 1) s += __shfl_xor(s, off, 64);
  if ((t & 63) == 0) rbuf[4 + (t >> 6)] = s;
  __syncthreads();
  if (t == 0) MS[1] = rbuf[4] + rbuf[5] + rbuf[6] + rbuf[7];
  __syncthreads();
  aw[b * SS + t] = e / MS[1];
}

// ---- context (h-split) + assemble y = [state, context] ----
__global__ void k_context(const float* __restrict__ aw, const float* __restrict__ enc,
                          const float* __restrict__ state, float* __restrict__ y) {
  const int b = blockIdx.x, hc = blockIdx.y, t = threadIdx.x;  // 128 threads
  __shared__ float aws[SS];
  aws[t] = aw[b * SS + t];
  aws[t + 128] = aw[b * SS + t + 128];
  __syncthreads();
  int h = hc * 128 + t;
  float acc = 0.f;
  for (int s = 0; s < SS; ++s) acc += aws[s] * enc[((size_t)b * SS + s) * HH + h];
  y[(size_t)b * 1024 + HH + h] = acc;
  y[(size_t)b * 1024 + h] = state[b * HH + h];
}

// ---- rowstat partials over score_g chunks ----
__global__ void k_rowstat_part(const float* __restrict__ sg,
                               float* __restrict__ pmax, float* __restrict__ psum) {
  const int b = blockIdx.x, c = blockIdx.y, t = threadIdx.x;
  __shared__ float rbuf[8];
  __shared__ float MS[1];
  const float* row = sg + (size_t)b * VV;
  const int base = c * 6250, end = base + 6250;
  float m = -1e30f;
  for (int i = base + t; i < end; i += 256) m = fmaxf(m, row[i]);
  for (int off = 32; off > 0; off >>= 1) m = fmaxf(m, __shfl_xor(m, off, 64));
  if ((t & 63) == 0) rbuf[t >> 6] = m;
  __syncthreads();
  if (t == 0) MS[0] = fmaxf(fmaxf(rbuf[0], rbuf[1]), fmaxf(rbuf[2], rbuf[3]));
  __syncthreads();
  float M = MS[0];
  float s = 0.f;
  for (int i = base + t; i < end; i += 256) s += __expf(row[i] - M);
  for (int off = 32; off > 0; off >>= 1) s += __shfl_xor(s, off, 64);
  if ((t & 63) == 0) rbuf[4 + (t >> 6)] = s;
  __syncthreads();
  if (t == 0) {
    pmax[b * 8 + c] = M;
    psum[b * 8 + c] = rbuf[4] + rbuf[5] + rbuf[6] + rbuf[7];
  }
}

// ---- merge partials + sc (online-softmax combine), one wave per b ----
__global__ void k_rowstat_final(const float* __restrict__ pmax, const float* __restrict__ psum,
                                const float* __restrict__ sc,
                                float* __restrict__ rmax, float* __restrict__ rsum) {
  const int b = blockIdx.x, t = threadIdx.x;  // 64 threads
  float m = -1e30f;
  if (t < 8) m = pmax[b * 8 + t];
  for (int i = t; i < SS; i += 64) m = fmaxf(m, sc[b * SS + i]);
  for (int off = 32; off > 0; off >>= 1) m = fmaxf(m, __shfl_xor(m, off, 64));
  float M = m;
  float s = 0.f;
  if (t < 8) s = psum[b * 8 + t] * __expf(pmax[b * 8 + t] - M);
  for (int i = t; i < SS; i += 64) s += __expf(sc[b * SS + i] - M);
  for (int off = 32; off > 0; off >>= 1) s += __shfl_xor(s, off, 64);
  if (t == 0) {
    rmax[b] = M;
    rsum[b] = s;
  }
}

__global__ void k_write_probg(const float* __restrict__ sg,
                              const float* __restrict__ rmax,
                              const float* __restrict__ rsum,
                              float* __restrict__ out) {
  int i = blockIdx.x * 256 + threadIdx.x;
  const int total = BB * VEXT;
  if (i >= total) return;
  int b = i / VEXT;
  int v = i - b * VEXT;
  float val;
  if (v < VV)
    val = __expf(sg[(size_t)b * VV + v] - rmax[b]) / rsum[b];
  else
    val = 1e-4f;
  out[i] = val;
}

__global__ void k_probc(const float* __restrict__ sc,
                        const int* __restrict__ enc_idx,
                        const float* __restrict__ rmax,
                        const float* __restrict__ rsum,
                        float* __restrict__ prob_c,
                        float* __restrict__ out,
                        float* __restrict__ pc_total) {
  const int b = blockIdx.x, t = threadIdx.x;
  __shared__ float rbuf[8];
  float pc = __expf(sc[b * SS + t] - rmax[b]) / rsum[b];
  prob_c[b * SS + t] = pc;
  atomicAdd(&out[(size_t)b * VEXT + enc_idx[b * SS + t]], pc);
  float s = pc;
  for (int off = 32; off > 0; off >>= 1) s += __shfl_down(s, off, 64);
  if ((t & 63) == 0) rbuf[t >> 6] = s;
  __syncthreads();
  if (t == 0) atomicAdd(pc_total, rbuf[0] + rbuf[1] + rbuf[2] + rbuf[3]);
}

// ---- weighted_new (h-split) ----
__global__ void k_weighted(const int* __restrict__ enc_idx,
                           const int* __restrict__ input_idx,
                           const float* __restrict__ prob_c,
                           const float* __restrict__ pc_total,
                           const float* __restrict__ enc,
                           float* __restrict__ wout) {
  const int b = blockIdx.x, hc = blockIdx.y, t = threadIdx.x;  // 128 threads
  __shared__ float f[SS];
  __shared__ float rb[2];
  const int idx_in = input_idx[b];
  int m0 = (enc_idx[b * SS + t] == idx_in) ? 1 : 0;
  int m1 = (enc_idx[b * SS + t + 128] == idx_in) ? 1 : 0;
  float lsum = (float)(m0 + m1);
  for (int off = 32; off > 0; off >>= 1) lsum += __shfl_xor(lsum, off, 64);
  if ((t & 63) == 0) rb[t >> 6] = lsum;
  __syncthreads();
  float tot = rb[0] + rb[1];
  float norm = (tot > 1.0f) ? 1.0f / tot : 1.0f;
  float inv_pct = 1.0f / pc_total[0];
  f[t] = m0 ? prob_c[b * SS + t] * inv_pct * norm : 0.f;
  f[t + 128] = m1 ? prob_c[b * SS + t + 128] * inv_pct * norm : 0.f;
  __syncthreads();
  int h = hc * 128 + t;
  float acc = 0.f;
  for (int s = 0; s < SS; ++s) acc += f[s] * enc[((size_t)b * SS + s) * HH + h];
  wout[b * HH + h] = acc;
}

extern "C" void kernel_launch(void* const* d_in, const int* in_sizes, int n_in,
                              void* d_out, int out_size, void* d_ws, size_t ws_size,
                              hipStream_t stream) {
  const int* input_idx = (const int*)d_in[0];
  const float* encoded = (const float*)d_in[1];
  const int* encoded_idx = (const int*)d_in[2];
  const float* prev_state = (const float*)d_in[3];
  const float* embed = (const float*)d_in[5];
  const float* Ws_w = (const float*)d_in[6];
  const float* Ws_b = (const float*)d_in[7];
  const float* gWih = (const float*)d_in[8];
  const float* gWhh = (const float*)d_in[9];
  const float* gbih = (const float*)d_in[10];
  const float* gbhh = (const float*)d_in[11];
  const float* attn_W = (const float*)d_in[12];
  const float* attn_b = (const float*)d_in[13];
  const float* attn_v = (const float*)d_in[14];
  const float* Wo_w = (const float*)d_in[15];
  const float* Wo_b = (const float*)d_in[16];
  const float* Wc_w = (const float*)d_in[17];
  const float* Wc_b = (const float*)d_in[18];

  float* out = (float*)d_out;
  float* out_state = out + (size_t)BB * VEXT;
  float* out_weighted = out_state + BB * HH;

  float* ws = (float*)d_ws;
  float* prev = ws;                       // 65536
  float* state = prev + BB * HH;          // 65536
  float* hW = state + BB * HH;            // 65536
  float* ascore = hW + BB * HH;           // 32768
  float* aw = ascore + BB * SS;           // 32768
  float* y = aw + BB * SS;                // 131072
  float* sg = y + BB * 1024;              // 6400000
  float* sc = sg + (size_t)BB * VV;       // 32768
  float* prob_c = sc + BB * SS;           // 32768
  float* pmax = prob_c + BB * SS;         // 1024
  float* psum = pmax + BB * 8;            // 1024
  float* rmax = psum + BB * 8;            // 128
  float* rsum = rmax + BB;                // 128
  float* pc_total = rsum + BB;            // 64 (padded)
  __hip_bfloat16* wc_bf = (__hip_bfloat16*)(pc_total + 64);       // 1024*512 bf16
  __hip_bfloat16* wa_bf = wc_bf + (size_t)1024 * HH;              // 512*512 bf16

  hipMemsetAsync(pc_total, 0, sizeof(float), stream);

  k_cvt_wc<<<512, 256, 0, stream>>>(Wc_w, wc_bf);
  k_cvt_wa2<<<256, 256, 0, stream>>>(attn_W, wa_bf);

  k_prev<<<BB, 256, 0, stream>>>(prev_state, Ws_w, Ws_b, prev);
  k_gru<<<BB, 256, 0, stream>>>(input_idx, embed, prev, gWih, gWhh, gbih, gbhh,
                                state, out_state);
  k_hw<<<BB, 256, 0, stream>>>(state, attn_W, attn_b, hW);

  k_fused<HH, 0><<<dim3(BB, SS / 32), 256, 0, stream>>>(encoded, wa_bf, hW, attn_v,
                                                        nullptr, ascore);
  k_attn_softmax<<<BB, 256, 0, stream>>>(ascore, aw);
  k_context<<<dim3(BB, 4), 128, 0, stream>>>(aw, encoded, state, y);

  k_score_g_mfma<<<(VV + 63) / 64, 256, 0, stream>>>(y, Wo_w, Wo_b, sg);
  k_fused<1024, 1><<<dim3(BB, SS / 32), 256, 0, stream>>>(encoded, wc_bf, Wc_b, y,
                                                          encoded_idx, sc);

  k_rowstat_part<<<dim3(BB, 8), 256, 0, stream>>>(sg, pmax, psum);
  k_rowstat_final<<<BB, 64, 0, stream>>>(pmax, psum, sc, rmax, rsum);
  k_write_probg<<<(BB * VEXT + 255) / 256, 256, 0, stream>>>(sg, rmax, rsum, out);
  k_probc<<<BB, 256, 0, stream>>>(sc, encoded_idx, rmax, rsum, prob_c, out, pc_total);
  k_weighted<<<dim3(BB, 4), 128, 0, stream>>>(encoded_idx, input_idx, prob_c, pc_total,
                                              encoded, out_weighted);
}

// Round 3
// 955.414 us; speedup vs baseline: 2.6664x; 1.2212x over previous
//
#include <hip/hip_runtime.h>
#include <hip/hip_bf16.h>
#include <math.h>

#define BB 128
#define SS 256
#define HH 512
#define VV 50000
#define VEXT 50012

typedef __bf16 bf16x8 __attribute__((ext_vector_type(8)));
typedef float f32x4 __attribute__((ext_vector_type(4)));

__device__ __forceinline__ float fast_tanh(float x) {
  float e = __expf(2.0f * x);
  return 1.0f - 2.0f / (e + 1.0f);
}
__device__ __forceinline__ float fast_sigmoid(float x) {
  return 1.0f / (1.0f + __expf(-x));
}
__device__ __forceinline__ bf16x8 cvt8(const float* p) {
  float4 a = *(const float4*)p;
  float4 b = *(const float4*)(p + 4);
  bf16x8 r;
  r[0] = (__bf16)a.x; r[1] = (__bf16)a.y; r[2] = (__bf16)a.z; r[3] = (__bf16)a.w;
  r[4] = (__bf16)b.x; r[5] = (__bf16)b.y; r[6] = (__bf16)b.z; r[7] = (__bf16)b.w;
  return r;
}

// ---- weight bf16 pre-conversion ----
__global__ void k_cvt_wc(const float* __restrict__ w, __hip_bfloat16* __restrict__ o) {
  int i = blockIdx.x * 256 + threadIdx.x;  // 131072 float4s
  if (i >= 131072) return;
  float4 v = ((const float4*)w)[i];
  __hip_bfloat16* d = o + i * 4;
  d[0] = __float2bfloat16(v.x); d[1] = __float2bfloat16(v.y);
  d[2] = __float2bfloat16(v.z); d[3] = __float2bfloat16(v.w);
}
__global__ void k_cvt_wa2(const float* __restrict__ attn_W, __hip_bfloat16* __restrict__ o) {
  int i = blockIdx.x * 256 + threadIdx.x;  // 65536 float4s over [512][512] extract
  if (i >= 65536) return;
  int j = i >> 7, c4 = i & 127;
  float4 v = *(const float4*)(attn_W + (size_t)j * 1024 + HH + c4 * 4);
  __hip_bfloat16* d = o + (size_t)j * HH + c4 * 4;
  d[0] = __float2bfloat16(v.x); d[1] = __float2bfloat16(v.y);
  d[2] = __float2bfloat16(v.z); d[3] = __float2bfloat16(v.w);
}

// ---- generic MFMA GEMM: C(128 x N) = A(128x512) @ B(N rows, stride LDB, first 512 cols).T + bias
// A fp32 (row stride 512; if GATHER, row i = Abase + gidx[i]*512), staged->bf16 LDS per 64-K chunk.
template <int LDB, bool GATHER>
__global__ __launch_bounds__(256, 2) void k_gemm_bt(
    const float* __restrict__ A, const float* __restrict__ B,
    const float* __restrict__ bias, float* __restrict__ C, int ldc,
    const int* __restrict__ gidx) {
  __shared__ __hip_bfloat16 ylds[128 * 72];
  const int t = threadIdx.x;
  const int l = t & 63, w = t >> 6;
  const int m = l & 15, q = l >> 4;
  const int n = blockIdx.x * 64 + w * 16 + m;
  const float* wrow = B + (size_t)n * LDB;
  f32x4 acc[8];
#pragma unroll
  for (int mt = 0; mt < 8; ++mt) acc[mt] = (f32x4){0.f, 0.f, 0.f, 0.f};

  for (int kt = 0; kt < 512; kt += 64) {
    __syncthreads();
#pragma unroll
    for (int i = 0; i < 8; ++i) {
      int f = t + i * 256;
      int row = f >> 4, c4 = f & 15;
      const float* arow;
      if (GATHER)
        arow = A + (size_t)gidx[row] * 512;
      else
        arow = A + (size_t)row * 512;
      float4 v = *(const float4*)(arow + kt + c4 * 4);
      __hip_bfloat16* d = ylds + row * 72 + c4 * 4;
      d[0] = __float2bfloat16(v.x); d[1] = __float2bfloat16(v.y);
      d[2] = __float2bfloat16(v.z); d[3] = __float2bfloat16(v.w);
    }
    __syncthreads();
#pragma unroll
    for (int ksl = 0; ksl < 2; ++ksl) {
      bf16x8 bfr = cvt8(wrow + kt + ksl * 32 + q * 8);
#pragma unroll
      for (int mt = 0; mt < 8; ++mt) {
        bf16x8 af = *(const bf16x8*)(ylds + (mt * 16 + m) * 72 + ksl * 32 + q * 8);
        acc[mt] = __builtin_amdgcn_mfma_f32_16x16x32_bf16(af, bfr, acc[mt], 0, 0, 0);
      }
    }
  }
  float bv = bias[n];
#pragma unroll
  for (int mt = 0; mt < 8; ++mt) {
#pragma unroll
    for (int r = 0; r < 4; ++r) {
      int rowm = mt * 16 + q * 4 + r;
      C[(size_t)rowm * ldc + n] = acc[mt][r] + bv;
    }
  }
}

// ---- GRU gates elementwise ----
__global__ void k_gates(const float* __restrict__ gi, const float* __restrict__ gh,
                        const float* __restrict__ prevv, float* __restrict__ state,
                        float* __restrict__ state_out) {
  int i = blockIdx.x * 256 + threadIdx.x;  // 65536
  int b = i >> 9, h = i & 511;
  const float* gib = gi + (size_t)b * 1536;
  const float* ghb = gh + (size_t)b * 1536;
  float ir = gib[h], iz = gib[512 + h], inn = gib[1024 + h];
  float hr = ghb[h], hz = ghb[512 + h], hn = ghb[1024 + h];
  float r = fast_sigmoid(ir + hr);
  float z = fast_sigmoid(iz + hz);
  float n = fast_tanh(inn + r * hn);
  float st = (1.f - z) * n + z * prevv[i];
  state[i] = st;
  state_out[i] = st;
}

// ---- fused MFMA kernel: out[b,s] = sum_n tanh(enc[b,s,:].W[n,:] + bias[n]) * mult[n]
// MODE 0: attn (bias = hW[b,:], mult = attn_v), MODE 1: score_c (bias = Wc_b, mult = y[b,:], +mask)
template <int NTOT, int MODE>
__global__ __launch_bounds__(256, 2) void k_fused(
    const float* __restrict__ enc, const __hip_bfloat16* __restrict__ Wbf,
    const float* __restrict__ biasA, const float* __restrict__ multA,
    const int* __restrict__ enc_idx, float* __restrict__ out) {
  const int b = blockIdx.x, s0 = blockIdx.y * 32, t = threadIdx.x;
  const int l = t & 63, w = t >> 6;
  const int wm = w & 1, wn = w >> 1;
  const int m = l & 15, q = l >> 4;
  const int row = s0 + wm * 16 + m;
  const float* erow = enc + ((size_t)b * SS + row) * HH;
  bf16x8 afr[16];
#pragma unroll
  for (int ks = 0; ks < 16; ++ks) afr[ks] = cvt8(erow + ks * 32 + q * 8);

  const float* bias_base = (MODE == 0) ? biasA + (size_t)b * HH : biasA;
  const float* mult_base = (MODE == 0) ? multA : multA + (size_t)b * 1024;

  float part[4] = {0.f, 0.f, 0.f, 0.f};
  for (int nb = 0; nb < NTOT; nb += 32) {
    const int n = nb + wn * 16 + m;
    const __hip_bfloat16* wrow = Wbf + (size_t)n * HH;
    f32x4 acc = {0.f, 0.f, 0.f, 0.f};
#pragma unroll
    for (int ks = 0; ks < 16; ++ks) {
      bf16x8 bfr = *(const bf16x8*)(wrow + ks * 32 + q * 8);
      acc = __builtin_amdgcn_mfma_f32_16x16x32_bf16(afr[ks], bfr, acc, 0, 0, 0);
    }
    float bias = bias_base[n];
    float mul = mult_base[n];
#pragma unroll
    for (int r = 0; r < 4; ++r) part[r] += fast_tanh(acc[r] + bias) * mul;
  }
#pragma unroll
  for (int r = 0; r < 4; ++r) {
    part[r] += __shfl_xor(part[r], 1, 64);
    part[r] += __shfl_xor(part[r], 2, 64);
    part[r] += __shfl_xor(part[r], 4, 64);
    part[r] += __shfl_xor(part[r], 8, 64);
  }
  __shared__ float red[2][32];
  if (m == 0) {
#pragma unroll
    for (int r = 0; r < 4; ++r) red[wn][wm * 16 + q * 4 + r] = part[r];
  }
  __syncthreads();
  if (t < 32) {
    float v = red[0][t] + red[1][t];
    int s = s0 + t;
    if (MODE == 1 && enc_idx[b * SS + s] == 0) v -= 1000.0f;
    out[b * SS + s] = v;
  }
}

// ---- score_g via MFMA: sg(128 x 50000) = y(128x1024) @ Wo_w^T ----
__global__ __launch_bounds__(256, 2) void k_score_g_mfma(
    const float* __restrict__ y, const float* __restrict__ Wo_w,
    const float* __restrict__ Wo_b, float* __restrict__ sg) {
  __shared__ __hip_bfloat16 ylds[128 * 72];
  const int t = threadIdx.x;
  const int l = t & 63, w = t >> 6;
  const int m = l & 15, q = l >> 4;
  const int nb = blockIdx.x * 64;
  const int n = nb + w * 16 + m;
  const int n_ld = (n < VV) ? n : (VV - 1);
  const float* wrow = Wo_w + (size_t)n_ld * 1024;
  f32x4 acc[8];
#pragma unroll
  for (int mt = 0; mt < 8; ++mt) acc[mt] = (f32x4){0.f, 0.f, 0.f, 0.f};

  for (int kt = 0; kt < 1024; kt += 64) {
    __syncthreads();
#pragma unroll
    for (int i = 0; i < 8; ++i) {
      int f = t + i * 256;
      int row = f >> 4, c4 = f & 15;
      float4 v = *(const float4*)(y + (size_t)row * 1024 + kt + c4 * 4);
      __hip_bfloat16* d = ylds + row * 72 + c4 * 4;
      d[0] = __float2bfloat16(v.x); d[1] = __float2bfloat16(v.y);
      d[2] = __float2bfloat16(v.z); d[3] = __float2bfloat16(v.w);
    }
    __syncthreads();
#pragma unroll
    for (int ksl = 0; ksl < 2; ++ksl) {
      bf16x8 bfr = cvt8(wrow + kt + ksl * 32 + q * 8);
#pragma unroll
      for (int mt = 0; mt < 8; ++mt) {
        bf16x8 af = *(const bf16x8*)(ylds + (mt * 16 + m) * 72 + ksl * 32 + q * 8);
        acc[mt] = __builtin_amdgcn_mfma_f32_16x16x32_bf16(af, bfr, acc[mt], 0, 0, 0);
      }
    }
  }
  if (n < VV) {
    float bias = Wo_b[n];
#pragma unroll
    for (int mt = 0; mt < 8; ++mt) {
#pragma unroll
      for (int r = 0; r < 4; ++r) {
        int rowm = mt * 16 + q * 4 + r;
        sg[(size_t)rowm * VV + n] = acc[mt][r] + bias;
      }
    }
  }
}

// ---- attention softmax -> aw ----
__global__ void k_attn_softmax(const float* __restrict__ score, float* __restrict__ aw) {
  const int b = blockIdx.x, t = threadIdx.x;
  __shared__ float rbuf[8];
  __shared__ float MS[2];
  float x = score[b * SS + t];
  float m = x;
  for (int off = 32; off > 0; off >>= 1) m = fmaxf(m, __shfl_xor(m, off, 64));
  if ((t & 63) == 0) rbuf[t >> 6] = m;
  __syncthreads();
  if (t == 0) MS[0] = fmaxf(fmaxf(rbuf[0], rbuf[1]), fmaxf(rbuf[2], rbuf[3]));
  __syncthreads();
  float e = __expf(x - MS[0]);
  float s = e;
  for (int off = 32; off > 0; off >>= 1) s += __shfl_xor(s, off, 64);
  if ((t & 63) == 0) rbuf[4 + (t >> 6)] = s;
  __syncthreads();
  if (t == 0) MS[1] = rbuf[4] + rbuf[5] + rbuf[6] + rbuf[7];
  __syncthreads();
  aw[b * SS + t] = e / MS[1];
}

// ---- context (h-split) + assemble y = [state, context] ----
__global__ void k_context(const float* __restrict__ aw, const float* __restrict__ enc,
                          const float* __restrict__ state, float* __restrict__ y) {
  const int b = blockIdx.x, hc = blockIdx.y, t = threadIdx.x;  // 128 threads
  __shared__ float aws[SS];
  aws[t] = aw[b * SS + t];
  aws[t + 128] = aw[b * SS + t + 128];
  __syncthreads();
  int h = hc * 128 + t;
  float acc = 0.f;
  for (int s = 0; s < SS; ++s) acc += aws[s] * enc[((size_t)b * SS + s) * HH + h];
  y[(size_t)b * 1024 + HH + h] = acc;
  y[(size_t)b * 1024 + h] = state[b * HH + h];
}

// ---- rowstat partials over score_g chunks ----
__global__ void k_rowstat_part(const float* __restrict__ sg,
                               float* __restrict__ pmax, float* __restrict__ psum) {
  const int b = blockIdx.x, c = blockIdx.y, t = threadIdx.x;
  __shared__ float rbuf[8];
  __shared__ float MS[1];
  const float* row = sg + (size_t)b * VV;
  const int base = c * 6250, end = base + 6250;
  float m = -1e30f;
  for (int i = base + t; i < end; i += 256) m = fmaxf(m, row[i]);
  for (int off = 32; off > 0; off >>= 1) m = fmaxf(m, __shfl_xor(m, off, 64));
  if ((t & 63) == 0) rbuf[t >> 6] = m;
  __syncthreads();
  if (t == 0) MS[0] = fmaxf(fmaxf(rbuf[0], rbuf[1]), fmaxf(rbuf[2], rbuf[3]));
  __syncthreads();
  float M = MS[0];
  float s = 0.f;
  for (int i = base + t; i < end; i += 256) s += __expf(row[i] - M);
  for (int off = 32; off > 0; off >>= 1) s += __shfl_xor(s, off, 64);
  if ((t & 63) == 0) rbuf[4 + (t >> 6)] = s;
  __syncthreads();
  if (t == 0) {
    pmax[b * 8 + c] = M;
    psum[b * 8 + c] = rbuf[4] + rbuf[5] + rbuf[6] + rbuf[7];
  }
}

// ---- merge partials + sc, one wave per b ----
__global__ void k_rowstat_final(const float* __restrict__ pmax, const float* __restrict__ psum,
                                const float* __restrict__ sc,
                                float* __restrict__ rmax, float* __restrict__ rsum) {
  const int b = blockIdx.x, t = threadIdx.x;  // 64 threads
  float m = -1e30f;
  if (t < 8) m = pmax[b * 8 + t];
  for (int i = t; i < SS; i += 64) m = fmaxf(m, sc[b * SS + i]);
  for (int off = 32; off > 0; off >>= 1) m = fmaxf(m, __shfl_xor(m, off, 64));
  float M = m;
  float s = 0.f;
  if (t < 8) s = psum[b * 8 + t] * __expf(pmax[b * 8 + t] - M);
  for (int i = t; i < SS; i += 64) s += __expf(sc[b * SS + i] - M);
  for (int off = 32; off > 0; off >>= 1) s += __shfl_xor(s, off, 64);
  if (t == 0) {
    rmax[b] = M;
    rsum[b] = s;
  }
}

__global__ void k_write_probg(const float* __restrict__ sg,
                              const float* __restrict__ rmax,
                              const float* __restrict__ rsum,
                              float* __restrict__ out) {
  int i = blockIdx.x * 256 + threadIdx.x;
  const int total = BB * VEXT;
  if (i >= total) return;
  int b = i / VEXT;
  int v = i - b * VEXT;
  float val;
  if (v < VV)
    val = __expf(sg[(size_t)b * VV + v] - rmax[b]) / rsum[b];
  else
    val = 1e-4f;
  out[i] = val;
}

__global__ void k_probc(const float* __restrict__ sc,
                        const int* __restrict__ enc_idx,
                        const float* __restrict__ rmax,
                        const float* __restrict__ rsum,
                        float* __restrict__ prob_c,
                        float* __restrict__ out,
                        float* __restrict__ pc_total) {
  const int b = blockIdx.x, t = threadIdx.x;
  __shared__ float rbuf[8];
  float pc = __expf(sc[b * SS + t] - rmax[b]) / rsum[b];
  prob_c[b * SS + t] = pc;
  atomicAdd(&out[(size_t)b * VEXT + enc_idx[b * SS + t]], pc);
  float s = pc;
  for (int off = 32; off > 0; off >>= 1) s += __shfl_down(s, off, 64);
  if ((t & 63) == 0) rbuf[t >> 6] = s;
  __syncthreads();
  if (t == 0) atomicAdd(pc_total, rbuf[0] + rbuf[1] + rbuf[2] + rbuf[3]);
}

// ---- weighted_new (h-split) ----
__global__ void k_weighted(const int* __restrict__ enc_idx,
                           const int* __restrict__ input_idx,
                           const float* __restrict__ prob_c,
                           const float* __restrict__ pc_total,
                           const float* __restrict__ enc,
                           float* __restrict__ wout) {
  const int b = blockIdx.x, hc = blockIdx.y, t = threadIdx.x;  // 128 threads
  __shared__ float f[SS];
  __shared__ float rb[2];
  const int idx_in = input_idx[b];
  int m0 = (enc_idx[b * SS + t] == idx_in) ? 1 : 0;
  int m1 = (enc_idx[b * SS + t + 128] == idx_in) ? 1 : 0;
  float lsum = (float)(m0 + m1);
  for (int off = 32; off > 0; off >>= 1) lsum += __shfl_xor(lsum, off, 64);
  if ((t & 63) == 0) rb[t >> 6] = lsum;
  __syncthreads();
  float tot = rb[0] + rb[1];
  float norm = (tot > 1.0f) ? 1.0f / tot : 1.0f;
  float inv_pct = 1.0f / pc_total[0];
  f[t] = m0 ? prob_c[b * SS + t] * inv_pct * norm : 0.f;
  f[t + 128] = m1 ? prob_c[b * SS + t + 128] * inv_pct * norm : 0.f;
  __syncthreads();
  int h = hc * 128 + t;
  float acc = 0.f;
  for (int s = 0; s < SS; ++s) acc += f[s] * enc[((size_t)b * SS + s) * HH + h];
  wout[b * HH + h] = acc;
}

extern "C" void kernel_launch(void* const* d_in, const int* in_sizes, int n_in,
                              void* d_out, int out_size, void* d_ws, size_t ws_size,
                              hipStream_t stream) {
  const int* input_idx = (const int*)d_in[0];
  const float* encoded = (const float*)d_in[1];
  const int* encoded_idx = (const int*)d_in[2];
  const float* prev_state = (const float*)d_in[3];
  const float* embed = (const float*)d_in[5];
  const float* Ws_w = (const float*)d_in[6];
  const float* Ws_b = (const float*)d_in[7];
  const float* gWih = (const float*)d_in[8];
  const float* gWhh = (const float*)d_in[9];
  const float* gbih = (const float*)d_in[10];
  const float* gbhh = (const float*)d_in[11];
  const float* attn_W = (const float*)d_in[12];
  const float* attn_b = (const float*)d_in[13];
  const float* attn_v = (const float*)d_in[14];
  const float* Wo_w = (const float*)d_in[15];
  const float* Wo_b = (const float*)d_in[16];
  const float* Wc_w = (const float*)d_in[17];
  const float* Wc_b = (const float*)d_in[18];

  float* out = (float*)d_out;
  float* out_state = out + (size_t)BB * VEXT;
  float* out_weighted = out_state + BB * HH;

  float* ws = (float*)d_ws;
  float* prevv = ws;                      // 65536
  float* state = prevv + BB * HH;         // 65536
  float* hW = state + BB * HH;            // 65536
  float* ascore = hW + BB * HH;           // 32768
  float* aw = ascore + BB * SS;           // 32768
  float* y = aw + BB * SS;                // 131072
  float* sg = y + BB * 1024;              // 6400000 (gi/gh alias its head pre-score_g)
  float* sc = sg + (size_t)BB * VV;       // 32768
  float* prob_c = sc + BB * SS;           // 32768
  float* pmax = prob_c + BB * SS;         // 1024
  float* psum = pmax + BB * 8;            // 1024
  float* rmax = psum + BB * 8;            // 128
  float* rsum = rmax + BB;                // 128
  float* pc_total = rsum + BB;            // 64 (padded)
  __hip_bfloat16* wc_bf = (__hip_bfloat16*)(pc_total + 64);
  __hip_bfloat16* wa_bf = wc_bf + (size_t)1024 * HH;

  float* gi = sg;                  // 128*1536, dead before sg is written
  float* gh = sg + BB * 1536;      // 128*1536

  hipMemsetAsync(pc_total, 0, sizeof(float), stream);

  k_cvt_wc<<<512, 256, 0, stream>>>(Wc_w, wc_bf);
  k_cvt_wa2<<<256, 256, 0, stream>>>(attn_W, wa_bf);

  // GRU chain via MFMA GEMMs
  k_gemm_bt<512, false><<<8, 256, 0, stream>>>(prev_state, Ws_w, Ws_b, prevv, 512, nullptr);
  k_gemm_bt<1024, true><<<24, 256, 0, stream>>>(embed, gWih, gbih, gi, 1536, input_idx);
  k_gemm_bt<512, false><<<24, 256, 0, stream>>>(prevv, gWhh, gbhh, gh, 1536, nullptr);
  k_gates<<<256, 256, 0, stream>>>(gi, gh, prevv, state, out_state);
  k_gemm_bt<1024, false><<<8, 256, 0, stream>>>(state, attn_W, attn_b, hW, 512, nullptr);

  k_fused<HH, 0><<<dim3(BB, SS / 32), 256, 0, stream>>>(encoded, wa_bf, hW, attn_v,
                                                        nullptr, ascore);
  k_attn_softmax<<<BB, 256, 0, stream>>>(ascore, aw);
  k_context<<<dim3(BB, 4), 128, 0, stream>>>(aw, encoded, state, y);

  k_score_g_mfma<<<(VV + 63) / 64, 256, 0, stream>>>(y, Wo_w, Wo_b, sg);
  k_fused<1024, 1><<<dim3(BB, SS / 32), 256, 0, stream>>>(encoded, wc_bf, Wc_b, y,
                                                          encoded_idx, sc);

  k_rowstat_part<<<dim3(BB, 8), 256, 0, stream>>>(sg, pmax, psum);
  k_rowstat_final<<<BB, 64, 0, stream>>>(pmax, psum, sc, rmax, rsum);
  k_write_probg<<<(BB * VEXT + 255) / 256, 256, 0, stream>>>(sg, rmax, rsum, out);
  k_probc<<<BB, 256, 0, stream>>>(sc, encoded_idx, rmax, rsum, prob_c, out, pc_total);
  k_weighted<<<dim3(BB, 4), 128, 0, stream>>>(encoded_idx, input_idx, prob_c, pc_total,
                                              encoded, out_weighted);
}

// Round 4
// 721.516 us; speedup vs baseline: 3.5308x; 1.3242x over previous
//
#include <hip/hip_runtime.h>
#include <hip/hip_bf16.h>
#include <math.h>

#define BB 128
#define SS 256
#define HH 512
#define VV 50000
#define VEXT 50012

typedef __bf16 bf16x8 __attribute__((ext_vector_type(8)));
typedef float f32x4 __attribute__((ext_vector_type(4)));

__device__ __forceinline__ float fast_tanh(float x) {
  float e = __expf(2.0f * x);
  return 1.0f - 2.0f / (e + 1.0f);
}
__device__ __forceinline__ float fast_sigmoid(float x) {
  return 1.0f / (1.0f + __expf(-x));
}
__device__ __forceinline__ bf16x8 cvt8(const float* p) {
  float4 a = *(const float4*)p;
  float4 b = *(const float4*)(p + 4);
  bf16x8 r;
  r[0] = (__bf16)a.x; r[1] = (__bf16)a.y; r[2] = (__bf16)a.z; r[3] = (__bf16)a.w;
  r[4] = (__bf16)b.x; r[5] = (__bf16)b.y; r[6] = (__bf16)b.z; r[7] = (__bf16)b.w;
  return r;
}

// ---- pack W rows into MFMA B-fragment order: dst[tile][ks][lane][8] bf16
// fragment (tile,ks,lane=(q*16+m)) = src[(tile*16+m)*ldw + coff + ks*32 + q*8 .. +8]
__global__ void k_pack_w(const float* __restrict__ src, int ldw, int coff, int icount,
                         __hip_bfloat16* __restrict__ dst) {
  int i = blockIdx.x * 256 + threadIdx.x;
  if (i >= icount) return;
  int l = i & 63, ks = (i >> 6) & 15, tile = i >> 10;
  int m = l & 15, q = l >> 4;
  const float* p = src + (size_t)(tile * 16 + m) * ldw + coff + ks * 32 + q * 8;
  *(bf16x8*)(dst + (size_t)i * 8) = cvt8(p);
}

// ---- pack encoded into A-fragment order: dst[b][st][ks][lane][8]
__global__ void k_pack_enc(const float* __restrict__ enc, __hip_bfloat16* __restrict__ epk) {
  int i = blockIdx.x * 256 + threadIdx.x;  // 128*16*16*64 = 2097152
  int l = i & 63, ks = (i >> 6) & 15, st = (i >> 10) & 15, b = i >> 14;
  int m = l & 15, q = l >> 4;
  const float* p = enc + ((size_t)b * SS + st * 16 + m) * HH + ks * 32 + q * 8;
  *(bf16x8*)(epk + (size_t)i * 8) = cvt8(p);
}

// ---- generic MFMA GEMM: C(128 x N) = A(128x512) @ B(N rows, stride LDB, first 512 cols).T + bias
template <int LDB, bool GATHER>
__global__ __launch_bounds__(256, 2) void k_gemm_bt(
    const float* __restrict__ A, const float* __restrict__ B,
    const float* __restrict__ bias, float* __restrict__ C, int ldc,
    const int* __restrict__ gidx) {
  __shared__ __hip_bfloat16 ylds[128 * 72];
  const int t = threadIdx.x;
  const int l = t & 63, w = t >> 6;
  const int m = l & 15, q = l >> 4;
  const int n = blockIdx.x * 64 + w * 16 + m;
  const float* wrow = B + (size_t)n * LDB;
  f32x4 acc[8];
#pragma unroll
  for (int mt = 0; mt < 8; ++mt) acc[mt] = (f32x4){0.f, 0.f, 0.f, 0.f};

  for (int kt = 0; kt < 512; kt += 64) {
    __syncthreads();
#pragma unroll
    for (int i = 0; i < 8; ++i) {
      int f = t + i * 256;
      int row = f >> 4, c4 = f & 15;
      const float* arow;
      if (GATHER)
        arow = A + (size_t)gidx[row] * 512;
      else
        arow = A + (size_t)row * 512;
      float4 v = *(const float4*)(arow + kt + c4 * 4);
      __hip_bfloat16* d = ylds + row * 72 + c4 * 4;
      d[0] = __float2bfloat16(v.x); d[1] = __float2bfloat16(v.y);
      d[2] = __float2bfloat16(v.z); d[3] = __float2bfloat16(v.w);
    }
    __syncthreads();
#pragma unroll
    for (int ksl = 0; ksl < 2; ++ksl) {
      bf16x8 bfr = cvt8(wrow + kt + ksl * 32 + q * 8);
#pragma unroll
      for (int mt = 0; mt < 8; ++mt) {
        bf16x8 af = *(const bf16x8*)(ylds + (mt * 16 + m) * 72 + ksl * 32 + q * 8);
        acc[mt] = __builtin_amdgcn_mfma_f32_16x16x32_bf16(af, bfr, acc[mt], 0, 0, 0);
      }
    }
  }
  float bv = bias[n];
#pragma unroll
  for (int mt = 0; mt < 8; ++mt) {
#pragma unroll
    for (int r = 0; r < 4; ++r) {
      int rowm = mt * 16 + q * 4 + r;
      C[(size_t)rowm * ldc + n] = acc[mt][r] + bv;
    }
  }
}

// ---- GRU gates elementwise ----
__global__ void k_gates(const float* __restrict__ gi, const float* __restrict__ gh,
                        const float* __restrict__ prevv, float* __restrict__ state,
                        float* __restrict__ state_out) {
  int i = blockIdx.x * 256 + threadIdx.x;  // 65536
  int b = i >> 9, h = i & 511;
  const float* gib = gi + (size_t)b * 1536;
  const float* ghb = gh + (size_t)b * 1536;
  float ir = gib[h], iz = gib[512 + h], inn = gib[1024 + h];
  float hr = ghb[h], hz = ghb[512 + h], hn = ghb[1024 + h];
  float r = fast_sigmoid(ir + hr);
  float z = fast_sigmoid(iz + hz);
  float n = fast_tanh(inn + r * hn);
  float st = (1.f - z) * n + z * prevv[i];
  state[i] = st;
  state_out[i] = st;
}

// ---- fused MFMA kernel: out[b,s] = sum_n tanh(enc[b,s,:].W[n,:] + bias[n]) * mult[n]
// A from epack (fragment order), B from wpk (fragment order). 4 independent acc chains.
// MODE 0: attn (bias = hW[b,:], mult = attn_v), MODE 1: score_c (bias = Wc_b, mult = y[b,:], +mask)
template <int NTOT, int MODE>
__global__ __launch_bounds__(256, 3) void k_fused(
    const __hip_bfloat16* __restrict__ epack, const __hip_bfloat16* __restrict__ wpk,
    const float* __restrict__ biasA, const float* __restrict__ multA,
    const int* __restrict__ enc_idx, float* __restrict__ out) {
  const int b = blockIdx.x, s0 = blockIdx.y * 32, t = threadIdx.x;
  const int l = t & 63, w = t >> 6;
  const int wm = w & 1, wn = w >> 1;
  const int m = l & 15, q = l >> 4;
  __shared__ float bias_l[NTOT];
  __shared__ float mult_l[NTOT];
  __shared__ float red[2][32];
  const float* bias_base = (MODE == 0) ? biasA + (size_t)b * HH : biasA;
  const float* mult_base = (MODE == 0) ? multA : multA + (size_t)b * 1024;
  for (int i = t; i < NTOT; i += 256) {
    bias_l[i] = bias_base[i];
    mult_l[i] = mult_base[i];
  }
  const int st = blockIdx.y * 2 + wm;
  const __hip_bfloat16* ep = epack + ((size_t)(b * 16 + st) * 16) * 512 + (size_t)l * 8;
  bf16x8 afr[16];
#pragma unroll
  for (int ks = 0; ks < 16; ++ks) afr[ks] = *(const bf16x8*)(ep + ks * 512);
  __syncthreads();

  float part[4] = {0.f, 0.f, 0.f, 0.f};
  for (int nb = 0; nb < NTOT; nb += 32) {
    const __hip_bfloat16* wp = wpk + ((size_t)((nb >> 4) + wn) * 16) * 512 + (size_t)l * 8;
    bf16x8 bfr[16];
#pragma unroll
    for (int ks = 0; ks < 16; ++ks) bfr[ks] = *(const bf16x8*)(wp + ks * 512);
    f32x4 a0 = {0.f, 0.f, 0.f, 0.f}, a1 = a0, a2 = a0, a3 = a0;
#pragma unroll
    for (int j = 0; j < 4; ++j) {
      a0 = __builtin_amdgcn_mfma_f32_16x16x32_bf16(afr[j], bfr[j], a0, 0, 0, 0);
      a1 = __builtin_amdgcn_mfma_f32_16x16x32_bf16(afr[4 + j], bfr[4 + j], a1, 0, 0, 0);
      a2 = __builtin_amdgcn_mfma_f32_16x16x32_bf16(afr[8 + j], bfr[8 + j], a2, 0, 0, 0);
      a3 = __builtin_amdgcn_mfma_f32_16x16x32_bf16(afr[12 + j], bfr[12 + j], a3, 0, 0, 0);
    }
    f32x4 acc = (a0 + a1) + (a2 + a3);
    const int n = nb + wn * 16 + m;
    float bias = bias_l[n];
    float mul = mult_l[n];
#pragma unroll
    for (int r = 0; r < 4; ++r) part[r] += fast_tanh(acc[r] + bias) * mul;
  }
#pragma unroll
  for (int r = 0; r < 4; ++r) {
    part[r] += __shfl_xor(part[r], 1, 64);
    part[r] += __shfl_xor(part[r], 2, 64);
    part[r] += __shfl_xor(part[r], 4, 64);
    part[r] += __shfl_xor(part[r], 8, 64);
  }
  if (m == 0) {
#pragma unroll
    for (int r = 0; r < 4; ++r) red[wn][wm * 16 + q * 4 + r] = part[r];
  }
  __syncthreads();
  if (t < 32) {
    float v = red[0][t] + red[1][t];
    int s = s0 + t;
    if (MODE == 1 && enc_idx[b * SS + s] == 0) v -= 1000.0f;
    out[b * SS + s] = v;
  }
}

// ---- score_g via MFMA: sg(128 x 50000) = y(128x1024) @ Wo_w^T ----
__global__ __launch_bounds__(256, 2) void k_score_g_mfma(
    const float* __restrict__ y, const float* __restrict__ Wo_w,
    const float* __restrict__ Wo_b, float* __restrict__ sg) {
  __shared__ __hip_bfloat16 ylds[128 * 72];
  const int t = threadIdx.x;
  const int l = t & 63, w = t >> 6;
  const int m = l & 15, q = l >> 4;
  const int nb = blockIdx.x * 64;
  const int n = nb + w * 16 + m;
  const int n_ld = (n < VV) ? n : (VV - 1);
  const float* wrow = Wo_w + (size_t)n_ld * 1024;
  f32x4 acc[8];
#pragma unroll
  for (int mt = 0; mt < 8; ++mt) acc[mt] = (f32x4){0.f, 0.f, 0.f, 0.f};

  for (int kt = 0; kt < 1024; kt += 64) {
    __syncthreads();
#pragma unroll
    for (int i = 0; i < 8; ++i) {
      int f = t + i * 256;
      int row = f >> 4, c4 = f & 15;
      float4 v = *(const float4*)(y + (size_t)row * 1024 + kt + c4 * 4);
      __hip_bfloat16* d = ylds + row * 72 + c4 * 4;
      d[0] = __float2bfloat16(v.x); d[1] = __float2bfloat16(v.y);
      d[2] = __float2bfloat16(v.z); d[3] = __float2bfloat16(v.w);
    }
    __syncthreads();
#pragma unroll
    for (int ksl = 0; ksl < 2; ++ksl) {
      bf16x8 bfr = cvt8(wrow + kt + ksl * 32 + q * 8);
#pragma unroll
      for (int mt = 0; mt < 8; ++mt) {
        bf16x8 af = *(const bf16x8*)(ylds + (mt * 16 + m) * 72 + ksl * 32 + q * 8);
        acc[mt] = __builtin_amdgcn_mfma_f32_16x16x32_bf16(af, bfr, acc[mt], 0, 0, 0);
      }
    }
  }
  if (n < VV) {
    float bias = Wo_b[n];
#pragma unroll
    for (int mt = 0; mt < 8; ++mt) {
#pragma unroll
      for (int r = 0; r < 4; ++r) {
        int rowm = mt * 16 + q * 4 + r;
        sg[(size_t)rowm * VV + n] = acc[mt][r] + bias;
      }
    }
  }
}

// ---- attention softmax -> aw ----
__global__ void k_attn_softmax(const float* __restrict__ score, float* __restrict__ aw) {
  const int b = blockIdx.x, t = threadIdx.x;
  __shared__ float rbuf[8];
  __shared__ float MS[2];
  float x = score[b * SS + t];
  float m = x;
  for (int off = 32; off > 0; off >>= 1) m = fmaxf(m, __shfl_xor(m, off, 64));
  if ((t & 63) == 0) rbuf[t >> 6] = m;
  __syncthreads();
  if (t == 0) MS[0] = fmaxf(fmaxf(rbuf[0], rbuf[1]), fmaxf(rbuf[2], rbuf[3]));
  __syncthreads();
  float e = __expf(x - MS[0]);
  float s = e;
  for (int off = 32; off > 0; off >>= 1) s += __shfl_xor(s, off, 64);
  if ((t & 63) == 0) rbuf[4 + (t >> 6)] = s;
  __syncthreads();
  if (t == 0) MS[1] = rbuf[4] + rbuf[5] + rbuf[6] + rbuf[7];
  __syncthreads();
  aw[b * SS + t] = e / MS[1];
}

// ---- context (h-split) + assemble y = [state, context] ----
__global__ void k_context(const float* __restrict__ aw, const float* __restrict__ enc,
                          const float* __restrict__ state, float* __restrict__ y) {
  const int b = blockIdx.x, hc = blockIdx.y, t = threadIdx.x;  // 128 threads
  __shared__ float aws[SS];
  aws[t] = aw[b * SS + t];
  aws[t + 128] = aw[b * SS + t + 128];
  __syncthreads();
  int h = hc * 128 + t;
  float acc = 0.f;
  for (int s = 0; s < SS; ++s) acc += aws[s] * enc[((size_t)b * SS + s) * HH + h];
  y[(size_t)b * 1024 + HH + h] = acc;
  y[(size_t)b * 1024 + h] = state[b * HH + h];
}

// ---- rowstat partials over score_g chunks ----
__global__ void k_rowstat_part(const float* __restrict__ sg,
                               float* __restrict__ pmax, float* __restrict__ psum) {
  const int b = blockIdx.x, c = blockIdx.y, t = threadIdx.x;
  __shared__ float rbuf[8];
  __shared__ float MS[1];
  const float* row = sg + (size_t)b * VV;
  const int base = c * 6250, end = base + 6250;
  float m = -1e30f;
  for (int i = base + t; i < end; i += 256) m = fmaxf(m, row[i]);
  for (int off = 32; off > 0; off >>= 1) m = fmaxf(m, __shfl_xor(m, off, 64));
  if ((t & 63) == 0) rbuf[t >> 6] = m;
  __syncthreads();
  if (t == 0) MS[0] = fmaxf(fmaxf(rbuf[0], rbuf[1]), fmaxf(rbuf[2], rbuf[3]));
  __syncthreads();
  float M = MS[0];
  float s = 0.f;
  for (int i = base + t; i < end; i += 256) s += __expf(row[i] - M);
  for (int off = 32; off > 0; off >>= 1) s += __shfl_xor(s, off, 64);
  if ((t & 63) == 0) rbuf[4 + (t >> 6)] = s;
  __syncthreads();
  if (t == 0) {
    pmax[b * 8 + c] = M;
    psum[b * 8 + c] = rbuf[4] + rbuf[5] + rbuf[6] + rbuf[7];
  }
}

// ---- merge partials + sc, one wave per b ----
__global__ void k_rowstat_final(const float* __restrict__ pmax, const float* __restrict__ psum,
                                const float* __restrict__ sc,
                                float* __restrict__ rmax, float* __restrict__ rsum) {
  const int b = blockIdx.x, t = threadIdx.x;  // 64 threads
  float m = -1e30f;
  if (t < 8) m = pmax[b * 8 + t];
  for (int i = t; i < SS; i += 64) m = fmaxf(m, sc[b * SS + i]);
  for (int off = 32; off > 0; off >>= 1) m = fmaxf(m, __shfl_xor(m, off, 64));
  float M = m;
  float s = 0.f;
  if (t < 8) s = psum[b * 8 + t] * __expf(pmax[b * 8 + t] - M);
  for (int i = t; i < SS; i += 64) s += __expf(sc[b * SS + i] - M);
  for (int off = 32; off > 0; off >>= 1) s += __shfl_xor(s, off, 64);
  if (t == 0) {
    rmax[b] = M;
    rsum[b] = s;
  }
}

__global__ void k_write_probg(const float* __restrict__ sg,
                              const float* __restrict__ rmax,
                              const float* __restrict__ rsum,
                              float* __restrict__ out) {
  int i = blockIdx.x * 256 + threadIdx.x;
  const int total = BB * VEXT;
  if (i >= total) return;
  int b = i / VEXT;
  int v = i - b * VEXT;
  float val;
  if (v < VV)
    val = __expf(sg[(size_t)b * VV + v] - rmax[b]) / rsum[b];
  else
    val = 1e-4f;
  out[i] = val;
}

__global__ void k_probc(const float* __restrict__ sc,
                        const int* __restrict__ enc_idx,
                        const float* __restrict__ rmax,
                        const float* __restrict__ rsum,
                        float* __restrict__ prob_c,
                        float* __restrict__ out,
                        float* __restrict__ pc_total) {
  const int b = blockIdx.x, t = threadIdx.x;
  __shared__ float rbuf[8];
  float pc = __expf(sc[b * SS + t] - rmax[b]) / rsum[b];
  prob_c[b * SS + t] = pc;
  atomicAdd(&out[(size_t)b * VEXT + enc_idx[b * SS + t]], pc);
  float s = pc;
  for (int off = 32; off > 0; off >>= 1) s += __shfl_down(s, off, 64);
  if ((t & 63) == 0) rbuf[t >> 6] = s;
  __syncthreads();
  if (t == 0) atomicAdd(pc_total, rbuf[0] + rbuf[1] + rbuf[2] + rbuf[3]);
}

// ---- weighted_new (h-split) ----
__global__ void k_weighted(const int* __restrict__ enc_idx,
                           const int* __restrict__ input_idx,
                           const float* __restrict__ prob_c,
                           const float* __restrict__ pc_total,
                           const float* __restrict__ enc,
                           float* __restrict__ wout) {
  const int b = blockIdx.x, hc = blockIdx.y, t = threadIdx.x;  // 128 threads
  __shared__ float f[SS];
  __shared__ float rb[2];
  const int idx_in = input_idx[b];
  int m0 = (enc_idx[b * SS + t] == idx_in) ? 1 : 0;
  int m1 = (enc_idx[b * SS + t + 128] == idx_in) ? 1 : 0;
  float lsum = (float)(m0 + m1);
  for (int off = 32; off > 0; off >>= 1) lsum += __shfl_xor(lsum, off, 64);
  if ((t & 63) == 0) rb[t >> 6] = lsum;
  __syncthreads();
  float tot = rb[0] + rb[1];
  float norm = (tot > 1.0f) ? 1.0f / tot : 1.0f;
  float inv_pct = 1.0f / pc_total[0];
  f[t] = m0 ? prob_c[b * SS + t] * inv_pct * norm : 0.f;
  f[t + 128] = m1 ? prob_c[b * SS + t + 128] * inv_pct * norm : 0.f;
  __syncthreads();
  int h = hc * 128 + t;
  float acc = 0.f;
  for (int s = 0; s < SS; ++s) acc += f[s] * enc[((size_t)b * SS + s) * HH + h];
  wout[b * HH + h] = acc;
}

extern "C" void kernel_launch(void* const* d_in, const int* in_sizes, int n_in,
                              void* d_out, int out_size, void* d_ws, size_t ws_size,
                              hipStream_t stream) {
  const int* input_idx = (const int*)d_in[0];
  const float* encoded = (const float*)d_in[1];
  const int* encoded_idx = (const int*)d_in[2];
  const float* prev_state = (const float*)d_in[3];
  const float* embed = (const float*)d_in[5];
  const float* Ws_w = (const float*)d_in[6];
  const float* Ws_b = (const float*)d_in[7];
  const float* gWih = (const float*)d_in[8];
  const float* gWhh = (const float*)d_in[9];
  const float* gbih = (const float*)d_in[10];
  const float* gbhh = (const float*)d_in[11];
  const float* attn_W = (const float*)d_in[12];
  const float* attn_b = (const float*)d_in[13];
  const float* attn_v = (const float*)d_in[14];
  const float* Wo_w = (const float*)d_in[15];
  const float* Wo_b = (const float*)d_in[16];
  const float* Wc_w = (const float*)d_in[17];
  const float* Wc_b = (const float*)d_in[18];

  float* out = (float*)d_out;
  float* out_state = out + (size_t)BB * VEXT;
  float* out_weighted = out_state + BB * HH;

  float* ws = (float*)d_ws;
  float* prevv = ws;                      // 65536
  float* state = prevv + BB * HH;         // 65536
  float* hW = state + BB * HH;            // 65536
  float* ascore = hW + BB * HH;           // 32768
  float* aw = ascore + BB * SS;           // 32768
  float* y = aw + BB * SS;                // 131072
  float* sg = y + BB * 1024;              // 6400000 (gi/gh alias its head pre-score_g)
  float* sc = sg + (size_t)BB * VV;       // 32768
  float* prob_c = sc + BB * SS;           // 32768
  float* pmax = prob_c + BB * SS;         // 1024
  float* psum = pmax + BB * 8;            // 1024
  float* rmax = psum + BB * 8;            // 128
  float* rsum = rmax + BB;                // 128
  float* pc_total = rsum + BB;            // 64 (padded)
  __hip_bfloat16* wc_bf = (__hip_bfloat16*)(pc_total + 64);       // 1024*512 (packed)
  __hip_bfloat16* wa_bf = wc_bf + (size_t)1024 * HH;              // 512*512 (packed)
  __hip_bfloat16* epack = wa_bf + (size_t)512 * HH;               // 128*256*512 (packed)

  float* gi = sg;                  // 128*1536, dead before sg is written
  float* gh = sg + BB * 1536;      // 128*1536

  hipMemsetAsync(pc_total, 0, sizeof(float), stream);

  // pack weights + encoded into MFMA fragment order (coalesced hot-loop loads)
  k_pack_w<<<256, 256, 0, stream>>>(Wc_w, 512, 0, 1024 * 64, wc_bf);
  k_pack_w<<<128, 256, 0, stream>>>(attn_W, 1024, 512, 512 * 64, wa_bf);
  k_pack_enc<<<8192, 256, 0, stream>>>(encoded, epack);

  // GRU chain via MFMA GEMMs
  k_gemm_bt<512, false><<<8, 256, 0, stream>>>(prev_state, Ws_w, Ws_b, prevv, 512, nullptr);
  k_gemm_bt<1024, true><<<24, 256, 0, stream>>>(embed, gWih, gbih, gi, 1536, input_idx);
  k_gemm_bt<512, false><<<24, 256, 0, stream>>>(prevv, gWhh, gbhh, gh, 1536, nullptr);
  k_gates<<<256, 256, 0, stream>>>(gi, gh, prevv, state, out_state);
  k_gemm_bt<1024, false><<<8, 256, 0, stream>>>(state, attn_W, attn_b, hW, 512, nullptr);

  k_fused<HH, 0><<<dim3(BB, 8), 256, 0, stream>>>(epack, wa_bf, hW, attn_v,
                                                  nullptr, ascore);
  k_attn_softmax<<<BB, 256, 0, stream>>>(ascore, aw);
  k_context<<<dim3(BB, 4), 128, 0, stream>>>(aw, encoded, state, y);

  k_score_g_mfma<<<(VV + 63) / 64, 256, 0, stream>>>(y, Wo_w, Wo_b, sg);
  k_fused<1024, 1><<<dim3(BB, 8), 256, 0, stream>>>(epack, wc_bf, Wc_b, y,
                                                    encoded_idx, sc);

  k_rowstat_part<<<dim3(BB, 8), 256, 0, stream>>>(sg, pmax, psum);
  k_rowstat_final<<<BB, 64, 0, stream>>>(pmax, psum, sc, rmax, rsum);
  k_write_probg<<<(BB * VEXT + 255) / 256, 256, 0, stream>>>(sg, rmax, rsum, out);
  k_probc<<<BB, 256, 0, stream>>>(sc, encoded_idx, rmax, rsum, prob_c, out, pc_total);
  k_weighted<<<dim3(BB, 4), 128, 0, stream>>>(encoded_idx, input_idx, prob_c, pc_total,
                                              encoded, out_weighted);
}